// Round 9
// baseline (464.313 us; speedup 1.0000x reference)
//
#include <hip/hip_runtime.h>
#include <hip/hip_bf16.h>

// ---------------------------------------------------------------------------
// UniPhyModel: B=1 T=8 C=4 IH=IW=256 P=16 -> HP=WP=16, D=256 (2D=512), L=2,
// NE=4, FF=1024.  Token n = t*256 + hp*16 + wp, channel c: <256 re, >=256 im.
// GEMMs: 64x64-tile bf16 MFMA 16x16x32, global_load_lds(16B) direct-to-LDS
// staging with XOR-swizzled layout (2-way-max bank aliasing), LDS double
// buffer, ONE barrier per K-iter.  Split-K for occupancy; combines folded
// into consumers.  Residuals bf16-only.  flux recurrence deleted (dead).
// ---------------------------------------------------------------------------

#define TOKS 2048
#define PSLICE 1048576  // partial slice stride (2048*512 fp32)

typedef __bf16 bf16;
typedef __attribute__((ext_vector_type(8))) __bf16 bf16x8;
typedef __attribute__((ext_vector_type(4))) __bf16 bf16x4;
typedef __attribute__((ext_vector_type(4))) float f32x4;

enum GMode { EENC = 0, ECONV, ESQ, ESQM, EMOE1, EMOE2, EDEC };

__device__ __forceinline__ void gload16(const void* g, void* l) {
  __builtin_amdgcn_global_load_lds(
      (const __attribute__((address_space(1))) unsigned int*)g,
      (__attribute__((address_space(3))) unsigned int*)l, 16, 0, 0);
}

// ---------- 64x64 tile GEMM (4 waves, each 32x32 = 2x2 frags) ----------
// LDS layout (per tile, 64 rows x 32 k bf16): 16B-unit index of (row, jj) =
// row*4 + (jj ^ ((row>>1)&3)); wave w stages rows [16w,16w+16): lane L ->
// row = 16w + (L>>2), jj = (L&3) ^ ((row>>1)&3)  => unit == 64w + L, i.e.
// exactly global_load_lds's base+lane*16 order.  Frag read banks: 2-way max.
template <int MODE, int SPLIT>
__global__ __launch_bounds__(256) void mgemm_k(
    const bf16* __restrict__ A, const bf16* __restrict__ Bt,
    const float* __restrict__ bias, const float* __restrict__ scalev,
    float* __restrict__ C, bf16* __restrict__ C16, float* __restrict__ Cpart,
    float* __restrict__ xmean, const float* __restrict__ zerop, int K, int N) {
  __shared__ __align__(16) bf16 As[2][2048];
  __shared__ __align__(16) bf16 Bs[2][2048];
  const int tid = threadIdx.x;
  const int bm = blockIdx.x * 64, bn = blockIdx.y * 64;
  const int lane = tid & 63, w = tid >> 6;
  const int wm = (w & 1) * 32, wn = (w >> 1) * 32;
  const int quad = lane >> 4, l16 = lane & 15;

  const int srow = w * 16 + (lane >> 2);
  const int sjj = (lane & 3) ^ ((srow >> 1) & 3);

  const int kbase = (SPLIT > 1) ? blockIdx.z * (K / SPLIT) : 0;
  const int kiter = K / (32 * SPLIT);
  if constexpr (MODE == EMOE1) Bt += (size_t)blockIdx.z * 524288;

  f32x4 acc[2][2] = {};

  int cv_t = 0, cv_h = 0, cv_w = 0;
  const bf16* aRow = nullptr;
  if constexpr (MODE == ECONV) {
    const int gm = bm + srow;
    cv_t = gm >> 8;
    cv_h = (gm >> 4) & 15;
    cv_w = gm & 15;
  } else {
    aRow = A + (size_t)(bm + srow) * K + kbase + sjj * 8;
  }
  const bf16* bRow = Bt + (size_t)(bn + srow) * K + kbase + sjj * 8;

  auto issue = [&](int kt, int buf) {
    const bf16* ga;
    if constexpr (MODE == ECONV) {
      const int gk0 = kbase + kt * 32;        // 32-chunk never crosses s
      const int s = gk0 >> 9;                 // lane-uniform
      const int kh = s / 3, kw = s - kh * 3;
      const int hh = cv_h + kh - 1, ww = cv_w + kw - 1;
      if (hh >= 0 && hh < 16 && ww >= 0 && ww < 16)
        ga = A + (size_t)(((cv_t << 8) + hh * 16 + ww) << 9) + (gk0 & 511) +
             sjj * 8;
      else
        ga = (const bf16*)zerop;  // zeroed page for halo
    } else {
      ga = aRow + kt * 32;
    }
    gload16(ga, &As[buf][w * 512]);
    gload16(bRow + kt * 32, &Bs[buf][w * 512]);
  };
  auto frag = [&](const bf16* S, int r) -> bf16x8 {
    const int unit = r * 4 + (quad ^ ((r >> 1) & 3));
    return *(const bf16x8*)&S[unit * 8];
  };

  issue(0, 0);
  for (int kt = 0; kt < kiter; kt++) {
    __syncthreads();  // drains loads into buf[kt&1]; prior compute done
    if (kt + 1 < kiter) issue(kt + 1, (kt + 1) & 1);
    const bf16* Ab = As[kt & 1];
    const bf16* Bb = Bs[kt & 1];
    const bf16x8 a0 = frag(Ab, wm + l16);
    const bf16x8 a1 = frag(Ab, wm + 16 + l16);
    const bf16x8 b0 = frag(Bb, wn + l16);
    const bf16x8 b1 = frag(Bb, wn + 16 + l16);
    acc[0][0] = __builtin_amdgcn_mfma_f32_16x16x32_bf16(a0, b0, acc[0][0], 0, 0, 0);
    acc[0][1] = __builtin_amdgcn_mfma_f32_16x16x32_bf16(a0, b1, acc[0][1], 0, 0, 0);
    acc[1][0] = __builtin_amdgcn_mfma_f32_16x16x32_bf16(a1, b0, acc[1][0], 0, 0, 0);
    acc[1][1] = __builtin_amdgcn_mfma_f32_16x16x32_bf16(a1, b1, acc[1][1], 0, 0, 0);
  }

  // epilogue; C/D layout: col = lane&15, row = quad*4 + reg
#pragma unroll
  for (int i = 0; i < 2; i++) {
#pragma unroll
    for (int j = 0; j < 2; j++) {
#pragma unroll
      for (int r = 0; r < 4; r++) {
        const int gm = bm + wm + i * 16 + quad * 4 + r;
        const int gn = bn + wn + j * 16 + l16;
        const float v = acc[i][j][r];
        if constexpr (SPLIT > 1) {
          Cpart[(size_t)blockIdx.z * PSLICE + (size_t)gm * 512 + gn] = v;
        } else if constexpr (MODE == EMOE1) {
          const float t = 0.7978845608028654f * (v + 0.044715f * v * v * v);
          const float g = 0.5f * v * (1.f + tanhf(t));
          const float p = scalev[gm * 4 + blockIdx.z];
          C16[(size_t)gm * 4096 + blockIdx.z * 1024 + gn] = (bf16)(p * g);
        } else {  // EDEC: scatter to (B,T,C,IH,IW)
          const int t = gm >> 8, hp = (gm >> 4) & 15, wp = gm & 15;
          const int c = gn >> 8, ph = (gn >> 4) & 15, pw = gn & 15;
          C[(size_t)(((t * 4 + c) * 256 + hp * 16 + ph) << 8) + wp * 16 + pw] =
              v + bias[gn];
        }
      }
    }
  }
  if constexpr (MODE == ESQM) {
    const int t = bm >> 8;  // 64-row tile lies within one t
#pragma unroll
    for (int j = 0; j < 2; j++) {
      float cs = 0.f;
#pragma unroll
      for (int i = 0; i < 2; i++)
#pragma unroll
        for (int r = 0; r < 4; r++) cs += acc[i][j][r];
      atomicAdd(&xmean[t * 512 + bn + wn + j * 16 + l16], cs);
    }
  }
}

// conv combine: xb16 = bf16(sum(8 partials) + bias + residual); zero xmean.
__global__ __launch_bounds__(256) void conv_ep_k(
    const float* __restrict__ parts, const float* __restrict__ bias,
    const bf16* __restrict__ resid16, bf16* __restrict__ xb16,
    float* __restrict__ xmean) {
  if (blockIdx.x < 16) xmean[blockIdx.x * 256 + threadIdx.x] = 0.f;
  const int i4 = (blockIdx.x * 256 + threadIdx.x) << 2;
  const int c = i4 & 511;
  const bf16x4 rz = *(const bf16x4*)&resid16[i4];
  const float4 bi = *(const float4*)&bias[c];
  float4 o = make_float4((float)rz[0] + bi.x, (float)rz[1] + bi.y,
                         (float)rz[2] + bi.z, (float)rz[3] + bi.w);
#pragma unroll
  for (int s = 0; s < 8; s++) {
    const float4 p = *(const float4*)&parts[(size_t)s * PSLICE + i4];
    o.x += p.x; o.y += p.y; o.z += p.z; o.w += p.w;
  }
  bf16x4 o16 = {(bf16)o.x, (bf16)o.y, (bf16)o.z, (bf16)o.w};
  *(bf16x4*)&xb16[i4] = o16;
}

// LN over 512 channels of (p0+p1 [+bias]); one wave/token, 4 tokens/block.
// ENC: +bias, raw residual -> zraw16, LN -> out16.
// !ENC: LN -> out16 + probs = softmax(ln @ Wr).
template <bool ENC>
__global__ __launch_bounds__(256) void ln_comb_k(
    const float* __restrict__ parts, const float* __restrict__ bias,
    const float* __restrict__ w, const float* __restrict__ b,
    const float* __restrict__ Wr, bf16* __restrict__ zraw16,
    bf16* __restrict__ out16, float* __restrict__ probs) {
  const int wv = threadIdx.x >> 6, lane = threadIdx.x & 63;
  const int n = (blockIdx.x << 2) + wv;
  float v[8];
  float s = 0.f, s2 = 0.f;
#pragma unroll
  for (int i = 0; i < 8; i++) {
    const int c = (i << 6) + lane;
    float x = parts[(size_t)n * 512 + c] + parts[PSLICE + (size_t)n * 512 + c];
    if constexpr (ENC) x += bias[c];
    v[i] = x;
    s += x;
    s2 += x * x;
  }
#pragma unroll
  for (int off = 32; off > 0; off >>= 1) {
    s += __shfl_down(s, off);
    s2 += __shfl_down(s2, off);
  }
  s = __shfl(s, 0);
  s2 = __shfl(s2, 0);
  const float m = s * (1.f / 512.f);
  const float var = s2 * (1.f / 512.f) - m * m;
  const float r = rsqrtf(var + 1e-5f);
  float a0 = 0.f, a1 = 0.f, a2 = 0.f, a3 = 0.f;
#pragma unroll
  for (int i = 0; i < 8; i++) {
    const int c = (i << 6) + lane;
    const float o = (v[i] - m) * r * w[c] + b[c];
    if constexpr (ENC) zraw16[(size_t)n * 512 + c] = (bf16)v[i];
    out16[(size_t)n * 512 + c] = (bf16)o;
    if constexpr (!ENC) {
      a0 += o * Wr[c * 4 + 0];
      a1 += o * Wr[c * 4 + 1];
      a2 += o * Wr[c * 4 + 2];
      a3 += o * Wr[c * 4 + 3];
    }
  }
  if constexpr (!ENC) {
#pragma unroll
    for (int off = 32; off > 0; off >>= 1) {
      a0 += __shfl_down(a0, off);
      a1 += __shfl_down(a1, off);
      a2 += __shfl_down(a2, off);
      a3 += __shfl_down(a3, off);
    }
    if (lane == 0) {
      const float mx = fmaxf(fmaxf(a0, a1), fmaxf(a2, a3));
      const float e0 = expf(a0 - mx), e1 = expf(a1 - mx), e2 = expf(a2 - mx),
                  e3 = expf(a3 - mx);
      const float inv = 1.f / (e0 + e1 + e2 + e3);
      probs[n * 4 + 0] = e0 * inv;
      probs[n * 4 + 1] = e1 * inv;
      probs[n * 4 + 2] = e2 * inv;
      probs[n * 4 + 3] = e3 * inv;
    }
  }
}

// final residual v = xb + xn + sum(8 MoE2 partials) (xb/xn bf16).
// DO_LN: raw -> zraw16 + LN(ln_sp next layer) -> out16.  else: out16 = bf16(v).
template <bool DO_LN>
__global__ __launch_bounds__(256) void addf2_k(
    const bf16* __restrict__ xb16, const bf16* __restrict__ xn16,
    const float* __restrict__ parts, const float* __restrict__ w,
    const float* __restrict__ b, bf16* __restrict__ zraw16,
    bf16* __restrict__ out16) {
  const int wv = threadIdx.x >> 6, lane = threadIdx.x & 63;
  const int n = (blockIdx.x << 2) + wv;
  float v[8];
  float s = 0.f, s2 = 0.f;
#pragma unroll
  for (int i = 0; i < 8; i++) {
    const size_t idx = (size_t)n * 512 + (i << 6) + lane;
    float x = (float)xb16[idx] + (float)xn16[idx];
#pragma unroll
    for (int sl = 0; sl < 8; sl++) x += parts[(size_t)sl * PSLICE + idx];
    v[i] = x;
    s += x;
    s2 += x * x;
  }
  if constexpr (!DO_LN) {
#pragma unroll
    for (int i = 0; i < 8; i++)
      out16[(size_t)n * 512 + (i << 6) + lane] = (bf16)v[i];
    return;
  }
#pragma unroll
  for (int off = 32; off > 0; off >>= 1) {
    s += __shfl_down(s, off);
    s2 += __shfl_down(s2, off);
  }
  s = __shfl(s, 0);
  s2 = __shfl(s2, 0);
  const float m = s * (1.f / 512.f);
  const float var = s2 * (1.f / 512.f) - m * m;
  const float r = rsqrtf(var + 1e-5f);
#pragma unroll
  for (int i = 0; i < 8; i++) {
    const int c = (i << 6) + lane;
    zraw16[(size_t)n * 512 + c] = (bf16)v[i];
    out16[(size_t)n * 512 + c] = (bf16)((v[i] - m) * r * w[c] + b[c]);
  }
}

// ---------- merged conversions: one launch, block-range decode ----------
__global__ __launch_bounds__(256) void cvt_all_k(
    const float* __restrict__ x, const float* __restrict__ Wenc,
    const float* __restrict__ Wdec, const float* __restrict__ W1,
    const float* __restrict__ W2, const float* __restrict__ E_re,
    const float* __restrict__ E_im, const float* __restrict__ Ed_re,
    const float* __restrict__ Ed_im, const float* __restrict__ conv_w,
    bf16* __restrict__ Ae, bf16* __restrict__ WencT, bf16* __restrict__ WdecT,
    bf16* __restrict__ W1T, bf16* __restrict__ W2Tc, bf16* __restrict__ MEt,
    bf16* __restrict__ convBt, float* __restrict__ zerop) {
  __shared__ float smem[4608];
  float(*tile)[33] = (float(*)[33])smem;
  const int tid = threadIdx.x;
  int b = blockIdx.x;
  const int tx = tid & 31, ty = tid >> 5;
  auto tpose = [&](const float* src, bf16* dst, int N, int dstride, int k0,
                   int n0) {
#pragma unroll
    for (int r = 0; r < 4; r++)
      tile[ty + 8 * r][tx] = src[(size_t)(k0 + ty + 8 * r) * N + n0 + tx];
    __syncthreads();
#pragma unroll
    for (int r = 0; r < 4; r++)
      dst[(size_t)(n0 + ty + 8 * r) * dstride + k0 + tx] =
          (bf16)tile[tx][ty + 8 * r];
  };
  if (b < 1024) {  // encoder patch gather + cast
    if (b == 0 && tid < 16) zerop[tid] = 0.f;  // halo zero page
    const int id = b * 256 + tid;
    const int n = id >> 7;
    const int kc = (id & 127) << 3;
    const int t = n >> 8, hp = (n >> 4) & 15, wp = n & 15;
    const int c = kc >> 8, ph = (kc >> 4) & 15, pw = kc & 15;
    const float* src =
        &x[(size_t)(((t * 4 + c) * 256 + hp * 16 + ph) << 8) + wp * 16 + pw];
    const float4 v0 = *(const float4*)src;
    const float4 v1 = *(const float4*)(src + 4);
    bf16* d = &Ae[(size_t)n * 1024 + kc];
    d[0] = (bf16)v0.x; d[1] = (bf16)v0.y; d[2] = (bf16)v0.z; d[3] = (bf16)v0.w;
    d[4] = (bf16)v1.x; d[5] = (bf16)v1.y; d[6] = (bf16)v1.z; d[7] = (bf16)v1.w;
    return;
  }
  b -= 1024;
  if (b < 512) {
    tpose(Wenc, WencT, 512, 1024, (b & 31) * 32, (b >> 5) * 32);
    return;
  }
  b -= 512;
  if (b < 512) {
    tpose(Wdec, WdecT, 1024, 512, (b & 15) * 32, (b >> 4) * 32);
    return;
  }
  b -= 512;
  if (b < 4096) {
    const int z = b >> 9, rem = b & 511;
    tpose(W1 + (size_t)z * 524288, W1T + (size_t)z * 524288, 1024, 512,
          (rem & 15) * 32, (rem >> 4) * 32);
    return;
  }
  b -= 4096;
  if (b < 4096) {
    const int z = b >> 9, rem = b & 511;
    const int l = z >> 2, e = z & 3;
    tpose(W2 + (size_t)z * 524288, W2Tc + (size_t)l * 2097152 + e * 1024, 512,
          4096, (rem & 31) * 32, (rem >> 5) * 32);
    return;
  }
  b -= 4096;
  if (b < 4096) {
    const int z = b >> 10;
    const int l = z >> 1, which = z & 1;
    const float* Er = (which ? Ed_re : E_re) + l * 65536;
    const float* Ei = (which ? Ed_im : E_im) + l * 65536;
    bf16* dst = MEt + (size_t)z * 262144;
    const int idx = (b & 1023) * 256 + tid;
    const int j = idx >> 9, k = idx & 511;
    const int kk = k & 255, jj = j & 255;
    const float er = Er[kk * 256 + jj], ei = Ei[kk * 256 + jj];
    const float v = (k < 256) ? ((j < 256) ? er : ei) : ((j < 256) ? -ei : er);
    dst[idx] = (bf16)v;
    return;
  }
  b -= 4096;
  {  // conv_w: one block per (l,co); coalesced read -> LDS -> coalesced write
    const int l = b >> 9, co = b & 511;
    const float* src = conv_w + (size_t)l * 2359296 + (size_t)co * 4608;
    bf16* d = convBt + (size_t)l * 2359296 + (size_t)co * 4608;
    for (int i = tid; i < 4608; i += 256) smem[i] = src[i];
    __syncthreads();
    for (int o = tid; o < 4608; o += 256) {
      const int s = o >> 9, ci = o & 511;
      d[o] = (bf16)smem[ci * 9 + s];
    }
  }
}

// Parallel src/gate from precomputed xmean sums. grid (8 t, 3 part) x 256.
__global__ __launch_bounds__(256) void srcgate_k(
    const float* __restrict__ xmean, const float* __restrict__ Wsr,
    const float* __restrict__ Wsi, const float* __restrict__ Wg,
    const float* __restrict__ bg, float* __restrict__ srcs,
    float* __restrict__ gts) {
  const int t = blockIdx.x, part = blockIdx.y, d = threadIdx.x;
  __shared__ float sxm[512];
  for (int c = d; c < 512; c += 256) sxm[c] = xmean[t * 512 + c] * (1.f / 256.f);
  __syncthreads();
  if (part == 0) {
    float s0 = 0.f, s1 = 0.f, s2 = 0.f, s3 = 0.f;
#pragma unroll 4
    for (int e = 0; e < 256; e += 4) {
      s0 += sxm[e + 0] * Wsr[(e + 0) * 256 + d] - sxm[256 + e + 0] * Wsi[(e + 0) * 256 + d];
      s1 += sxm[e + 1] * Wsr[(e + 1) * 256 + d] - sxm[256 + e + 1] * Wsi[(e + 1) * 256 + d];
      s2 += sxm[e + 2] * Wsr[(e + 2) * 256 + d] - sxm[256 + e + 2] * Wsi[(e + 2) * 256 + d];
      s3 += sxm[e + 3] * Wsr[(e + 3) * 256 + d] - sxm[256 + e + 3] * Wsi[(e + 3) * 256 + d];
    }
    srcs[t * 512 + d] = (s0 + s1) + (s2 + s3);
  } else if (part == 1) {
    float s0 = 0.f, s1 = 0.f, s2 = 0.f, s3 = 0.f;
#pragma unroll 4
    for (int e = 0; e < 256; e += 4) {
      s0 += sxm[e + 0] * Wsi[(e + 0) * 256 + d] + sxm[256 + e + 0] * Wsr[(e + 0) * 256 + d];
      s1 += sxm[e + 1] * Wsi[(e + 1) * 256 + d] + sxm[256 + e + 1] * Wsr[(e + 1) * 256 + d];
      s2 += sxm[e + 2] * Wsi[(e + 2) * 256 + d] + sxm[256 + e + 2] * Wsr[(e + 2) * 256 + d];
      s3 += sxm[e + 3] * Wsi[(e + 3) * 256 + d] + sxm[256 + e + 3] * Wsr[(e + 3) * 256 + d];
    }
    srcs[t * 512 + 256 + d] = (s0 + s1) + (s2 + s3);
  } else {
    float s0 = 0.f, s1 = 0.f, s2 = 0.f, s3 = 0.f;
#pragma unroll 4
    for (int c = 0; c < 512; c += 4) {
      s0 += sxm[c + 0] * Wg[(c + 0) * 256 + d];
      s1 += sxm[c + 1] * Wg[(c + 1) * 256 + d];
      s2 += sxm[c + 2] * Wg[(c + 2) * 256 + d];
      s3 += sxm[c + 3] * Wg[(c + 3) * 256 + d];
    }
    const float ga = (s0 + s1) + (s2 + s3) + bg[d];
    gts[t * 256 + d] = 1.f / (1.f + expf(-ga));
  }
}

// Per-(p,d) time scan over esq1 partials (2 slices); opd/opf inline.
template <bool FIRST>
__global__ __launch_bounds__(256) void time_scan_k(
    const float* __restrict__ parts, const float* __restrict__ gts,
    const float* __restrict__ srcs, const float* __restrict__ lamre,
    const float* __restrict__ lamim, const float* __restrict__ dt,
    bf16* __restrict__ hout16, float* __restrict__ hprev) {
  const int d = threadIdx.x;
  const int p = blockIdx.x;
  const float lr0 = lamre[d];
  const float sp = (lr0 > 20.f) ? lr0 : log1pf(expf(lr0));
  const float lre = -(sp + 0.01f);
  const float lim = lamim[d];
  const float den = lre * lre + lim * lim;
  float ar[8], ai[8], ofr[8], ofi[8];
#pragma unroll
  for (int t = 0; t < 8; t++) {
    const float dtv = dt[t];
    const float er = expf(lre * dtv);
    const float odr = er * cosf(lim * dtv);
    const float odi = er * sinf(lim * dtv);
    ar[t] = odr;
    ai[t] = odi;
    const float nr = odr - 1.f, ni = odi;
    ofr[t] = (nr * lre + ni * lim) / den;
    ofi[t] = (ni * lre - nr * lim) / den;
  }
  float hr = 0.f, hi = 0.f;
  float hpr = 0.f, hpi = 0.f;
  if constexpr (!FIRST) {
    hpr = hprev[p * 512 + d];
    hpi = hprev[p * 512 + 256 + d];
  }
  float o7r = 0.f, o7i = 0.f;
#pragma unroll
  for (int t = 0; t < 8; t++) {
    const size_t base = (size_t)((t << 8) + p) * 512;
    const float xr = parts[base + d] + parts[PSLICE + base + d];
    const float xi = parts[base + 256 + d] + parts[PSLICE + base + 256 + d];
    const float g = gts[t * 256 + d];
    const float sr = srcs[t * 512 + d], si = srcs[t * 512 + 256 + d];
    const float fr = xr * g + sr * (1.f - g);
    const float fi = xi * g + si * (1.f - g);
    const float ur = fr * ofr[t] - fi * ofi[t];
    const float ui = fr * ofi[t] + fi * ofr[t];
    const float nhr = ur + ar[t] * hr - ai[t] * hi;
    const float nhi = ui + ar[t] * hi + ai[t] * hr;
    hr = nhr;
    hi = nhi;
    const float outr = hr + ar[t] * hpr - ai[t] * hpi;
    const float outi = hi + ar[t] * hpi + ai[t] * hpr;
    hout16[base + d] = (bf16)outr;
    hout16[base + 256 + d] = (bf16)outi;
    if (t == 7) {
      o7r = outr;
      o7i = outi;
    }
  }
  hprev[p * 512 + d] = o7r;
  hprev[p * 512 + 256 + d] = o7i;
}

extern "C" void kernel_launch(void* const* d_in, const int* in_sizes, int n_in,
                              void* d_out, int out_size, void* d_ws,
                              size_t ws_size, hipStream_t stream) {
  const float* x_in = (const float*)d_in[0];
  const float* dt = (const float*)d_in[1];
  const float* Wenc = (const float*)d_in[2];
  const float* benc = (const float*)d_in[3];
  const float* Wdec = (const float*)d_in[4];
  const float* bdec = (const float*)d_in[5];
  const float* ln_sp_w = (const float*)d_in[6];
  const float* ln_sp_b = (const float*)d_in[7];
  const float* conv_w = (const float*)d_in[8];
  const float* conv_b = (const float*)d_in[9];
  const float* E_re = (const float*)d_in[10];
  const float* E_im = (const float*)d_in[11];
  const float* Ed_re = (const float*)d_in[12];
  const float* Ed_im = (const float*)d_in[13];
  const float* Ws_re = (const float*)d_in[14];
  const float* Ws_im = (const float*)d_in[15];
  const float* Wg = (const float*)d_in[16];
  const float* bg = (const float*)d_in[17];
  const float* lam_re = (const float*)d_in[18];
  const float* lam_im = (const float*)d_in[19];
  const float* ln_t_w = (const float*)d_in[20];
  const float* ln_t_b = (const float*)d_in[21];
  const float* Wr = (const float*)d_in[22];
  const float* W1 = (const float*)d_in[23];
  const float* W2 = (const float*)d_in[24];
  float* out = (float*)d_out;

  float* ws = (float*)d_ws;
  size_t off = 0;
  auto allocf = [&](size_t n) {
    float* p = ws + off;
    off += n;
    return p;
  };
  auto allocb = [&](size_t n) {
    bf16* p = (bf16*)(ws + off);
    off += n / 2;
    return p;
  };
  float* parts = allocf((size_t)8 * PSLICE);
  float* hprev = allocf(256 * 512);
  float* zerop = allocf(16);
  float* xm = allocf(8 * 512);
  float* srcs = allocf(8 * 512);
  float* gts = allocf(8 * 256);
  float* probs = allocf((size_t)TOKS * 4);
  bf16* zraw16 = allocb((size_t)TOKS * 512);
  bf16* znsp16 = allocb((size_t)TOKS * 512);
  bf16* xn16 = allocb((size_t)TOKS * 512);
  bf16* xb16 = allocb((size_t)TOKS * 512);
  bf16* z16 = allocb((size_t)TOKS * 512);
  bf16* hb16 = allocb((size_t)TOKS * 512);
  bf16* hid16 = allocb((size_t)TOKS * 4096);
  bf16* Aenc16 = allocb((size_t)TOKS * 1024);
  bf16* WencT = allocb((size_t)512 * 1024);
  bf16* WdecT = allocb((size_t)1024 * 512);
  bf16* MEt = allocb((size_t)4 * 512 * 512);
  bf16* convBt = allocb((size_t)2 * 512 * 4608);
  bf16* W1T = allocb((size_t)8 * 1024 * 512);
  bf16* W2Tc = allocb((size_t)2 * 512 * 4096);

  // ---- all conversions in one launch (also zeroes halo page) ----
  cvt_all_k<<<15360, 256, 0, stream>>>(x_in, Wenc, Wdec, W1, W2, E_re, E_im,
                                       Ed_re, Ed_im, conv_w, Aenc16, WencT,
                                       WdecT, W1T, W2Tc, MEt, convBt, zerop);

  // ---- encoder: split-K=2, combine folded into LN ----
  mgemm_k<EENC, 2><<<dim3(32, 8, 2), 256, 0, stream>>>(
      Aenc16, WencT, nullptr, nullptr, nullptr, nullptr, parts, nullptr, zerop,
      1024, 512);
  ln_comb_k<true><<<512, 256, 0, stream>>>(parts, benc, ln_sp_w, ln_sp_b,
                                           nullptr, zraw16, znsp16, nullptr);

  for (int l = 0; l < 2; l++) {
    mgemm_k<ECONV, 8><<<dim3(32, 8, 8), 256, 0, stream>>>(
        znsp16, convBt + (size_t)l * 2359296, nullptr, nullptr, nullptr,
        nullptr, parts, nullptr, zerop, 4608, 512);
    conv_ep_k<<<1024, 256, 0, stream>>>(parts, conv_b + l * 512, zraw16, xb16,
                                        xm);
    mgemm_k<ESQM, 2><<<dim3(32, 8, 2), 256, 0, stream>>>(
        xb16, MEt + (size_t)(l * 2) * 262144, nullptr, nullptr, nullptr,
        nullptr, parts, xm, zerop, 512, 512);
    srcgate_k<<<dim3(8, 3), 256, 0, stream>>>(xm, Ws_re + l * 65536,
                                              Ws_im + l * 65536,
                                              Wg + l * 131072, bg + l * 256,
                                              srcs, gts);
    if (l == 0)
      time_scan_k<true><<<256, 256, 0, stream>>>(parts, gts, srcs, lam_re,
                                                 lam_im, dt, hb16, hprev);
    else
      time_scan_k<false><<<256, 256, 0, stream>>>(parts, gts, srcs,
                                                  lam_re + 256, lam_im + 256,
                                                  dt, hb16, hprev);
    mgemm_k<ESQ, 2><<<dim3(32, 8, 2), 256, 0, stream>>>(
        hb16, MEt + (size_t)(l * 2 + 1) * 262144, nullptr, nullptr, nullptr,
        nullptr, parts, nullptr, zerop, 512, 512);
    ln_comb_k<false><<<512, 256, 0, stream>>>(parts, nullptr, ln_t_w + l * 512,
                                              ln_t_b + l * 512, Wr + l * 2048,
                                              nullptr, xn16, probs);
    mgemm_k<EMOE1, 1><<<dim3(32, 16, 4), 256, 0, stream>>>(
        xn16, W1T + (size_t)l * 2097152, nullptr, probs, nullptr, hid16,
        nullptr, nullptr, zerop, 512, 1024);
    mgemm_k<EMOE2, 8><<<dim3(32, 8, 8), 256, 0, stream>>>(
        hid16, W2Tc + (size_t)l * 2097152, nullptr, nullptr, nullptr, nullptr,
        parts, nullptr, zerop, 4096, 512);
    if (l == 0)
      addf2_k<true><<<512, 256, 0, stream>>>(xb16, xn16, parts, ln_sp_w + 512,
                                             ln_sp_b + 512, zraw16, znsp16);
    else
      addf2_k<false><<<512, 256, 0, stream>>>(xb16, xn16, parts, nullptr,
                                              nullptr, nullptr, z16);
  }

  // ---- decoder ----
  mgemm_k<EDEC, 1><<<dim3(32, 16), 256, 0, stream>>>(
      z16, WdecT, bdec, nullptr, out, nullptr, nullptr, nullptr, zerop, 512,
      1024);
}

// Round 10
// 443.475 us; speedup vs baseline: 1.0470x; 1.0470x over previous
//
#include <hip/hip_runtime.h>
#include <hip/hip_bf16.h>

// ---------------------------------------------------------------------------
// UniPhyModel: B=1 T=8 C=4 IH=IW=256 P=16 -> HP=WP=16, D=256 (2D=512), L=2,
// NE=4, FF=1024.  Token n = t*256 + hp*16 + wp, channel c: <256 re, >=256 im.
// GEMMs: 64x64-tile bf16 MFMA 16x16x32, register-prefetch staging (round-8
// structure, best measured).  Split-K for occupancy; fat GEMMs (conv/MoE2,
// split 8) store bf16 partials (halves partial HBM traffic); small GEMMs
// (enc/esq, split 2) keep fp32 partials.  Combines folded into consumers.
// Spatial mean via atomicAdd in esq1 epilogue.  flux recurrence dead-code.
// ---------------------------------------------------------------------------

#define TOKS 2048
#define PSLICE 1048576   // fp32 partial slice stride (2048*512)
#define BPSLICE 1048576  // bf16 partial slice stride (elements)

typedef __bf16 bf16;
typedef __attribute__((ext_vector_type(8))) __bf16 bf16x8;
typedef __attribute__((ext_vector_type(4))) __bf16 bf16x4;
typedef __attribute__((ext_vector_type(4))) float f32x4;

enum GMode { EENC = 0, ECONV, ESQ, ESQM, EMOE1, EMOE2, EDEC };

// ---------- 64x64 tile GEMM (4 waves, each 32x32 = 2x2 frags) ----------
// SPLIT>1: blockIdx.z = K-slice -> partials (fp32 Cpart or bf16 Cpart16).
// ESQM: also atomicAdd per-column tile sums into xmean[t*512+c].
// EMOE1: blockIdx.z = expert; gelu*probs epilogue, C16 row stride 4096.
template <int MODE, int SPLIT, bool BPART>
__global__ __launch_bounds__(256) void mgemm_k(
    const bf16* __restrict__ A, const bf16* __restrict__ Bt,
    const float* __restrict__ bias, const float* __restrict__ scalev,
    float* __restrict__ C, bf16* __restrict__ C16, float* __restrict__ Cpart,
    bf16* __restrict__ Cpart16, float* __restrict__ xmean, int K, int N) {
  __shared__ __align__(16) bf16 As[64 * 40];
  __shared__ __align__(16) bf16 Bs[64 * 40];
  const int tid = threadIdx.x;
  const int bm = blockIdx.x * 64, bn = blockIdx.y * 64;
  const int lane = tid & 63, w = tid >> 6;
  const int wm = (w & 1) * 32, wn = (w >> 1) * 32;
  const int quad = lane >> 4, l16 = lane & 15;
  const int srow = tid >> 2, sko = (tid & 3) << 3;

  const int kbase = (SPLIT > 1) ? blockIdx.z * (K / SPLIT) : 0;
  const int kiter = K / (32 * SPLIT);
  if constexpr (MODE == EMOE1) Bt += (size_t)blockIdx.z * 524288;

  f32x4 acc[2][2] = {};

  int cv_t = 0, cv_h = 0, cv_w = 0;
  if constexpr (MODE == ECONV) {
    const int gm = bm + srow;
    cv_t = gm >> 8;
    cv_h = (gm >> 4) & 15;
    cv_w = gm & 15;
  }

  auto loadA = [&](int kt) -> bf16x8 {
    const int gk = kbase + kt * 32 + sko;
    if constexpr (MODE == ECONV) {
      const int s = gk >> 9, ci = gk & 511;  // 8-chunk never crosses s
      const int kh = s / 3, kw = s - kh * 3;
      const int hh = cv_h + kh - 1, ww = cv_w + kw - 1;
      if (hh >= 0 && hh < 16 && ww >= 0 && ww < 16)
        return *(const bf16x8*)&A[(size_t)(((cv_t << 8) + hh * 16 + ww) << 9) +
                                  ci];
      bf16x8 zz;
#pragma unroll
      for (int q = 0; q < 8; q++) zz[q] = (bf16)0.0f;
      return zz;
    } else {
      return *(const bf16x8*)&A[(size_t)(bm + srow) * K + gk];
    }
  };
  auto loadB = [&](int kt) -> bf16x8 {
    return *(const bf16x8*)&Bt[(size_t)(bn + srow) * K + kbase + kt * 32 + sko];
  };

  bf16x8 pa = loadA(0), pb = loadB(0);
  for (int kt = 0; kt < kiter; kt++) {
    *(bf16x8*)&As[srow * 40 + sko] = pa;
    *(bf16x8*)&Bs[srow * 40 + sko] = pb;
    __syncthreads();
    if (kt + 1 < kiter) {
      pa = loadA(kt + 1);
      pb = loadB(kt + 1);
    }
    const bf16x8 a0 = *(const bf16x8*)&As[(wm + l16) * 40 + quad * 8];
    const bf16x8 a1 = *(const bf16x8*)&As[(wm + 16 + l16) * 40 + quad * 8];
    const bf16x8 b0 = *(const bf16x8*)&Bs[(wn + l16) * 40 + quad * 8];
    const bf16x8 b1 = *(const bf16x8*)&Bs[(wn + 16 + l16) * 40 + quad * 8];
    acc[0][0] = __builtin_amdgcn_mfma_f32_16x16x32_bf16(a0, b0, acc[0][0], 0, 0, 0);
    acc[0][1] = __builtin_amdgcn_mfma_f32_16x16x32_bf16(a0, b1, acc[0][1], 0, 0, 0);
    acc[1][0] = __builtin_amdgcn_mfma_f32_16x16x32_bf16(a1, b0, acc[1][0], 0, 0, 0);
    acc[1][1] = __builtin_amdgcn_mfma_f32_16x16x32_bf16(a1, b1, acc[1][1], 0, 0, 0);
    __syncthreads();
  }

  // epilogue; C/D layout: col = lane&15, row = quad*4 + reg
#pragma unroll
  for (int i = 0; i < 2; i++) {
#pragma unroll
    for (int j = 0; j < 2; j++) {
#pragma unroll
      for (int r = 0; r < 4; r++) {
        const int gm = bm + wm + i * 16 + quad * 4 + r;
        const int gn = bn + wn + j * 16 + l16;
        const float v = acc[i][j][r];
        if constexpr (SPLIT > 1) {
          if constexpr (BPART)
            Cpart16[(size_t)blockIdx.z * BPSLICE + (size_t)gm * 512 + gn] =
                (bf16)v;
          else
            Cpart[(size_t)blockIdx.z * PSLICE + (size_t)gm * 512 + gn] = v;
        } else if constexpr (MODE == EMOE1) {
          const float t = 0.7978845608028654f * (v + 0.044715f * v * v * v);
          const float g = 0.5f * v * (1.f + tanhf(t));
          const float p = scalev[gm * 4 + blockIdx.z];
          C16[(size_t)gm * 4096 + blockIdx.z * 1024 + gn] = (bf16)(p * g);
        } else {  // EDEC: scatter to (B,T,C,IH,IW)
          const int t = gm >> 8, hp = (gm >> 4) & 15, wp = gm & 15;
          const int c = gn >> 8, ph = (gn >> 4) & 15, pw = gn & 15;
          C[(size_t)(((t * 4 + c) * 256 + hp * 16 + ph) << 8) + wp * 16 + pw] =
              v + bias[gn];
        }
      }
    }
  }
  if constexpr (MODE == ESQM) {
    const int t = bm >> 8;  // 64-row tile lies within one t
#pragma unroll
    for (int j = 0; j < 2; j++) {
      float cs = 0.f;
#pragma unroll
      for (int i = 0; i < 2; i++)
#pragma unroll
        for (int r = 0; r < 4; r++) cs += acc[i][j][r];
      atomicAdd(&xmean[t * 512 + bn + wn + j * 16 + l16], cs);
    }
  }
}

// conv combine: xb16 = bf16(sum(8 bf16 partials) + bias + residual); zero xm.
__global__ __launch_bounds__(256) void conv_ep_k(
    const bf16* __restrict__ parts, const float* __restrict__ bias,
    const bf16* __restrict__ resid16, bf16* __restrict__ xb16,
    float* __restrict__ xmean) {
  if (blockIdx.x < 16) xmean[blockIdx.x * 256 + threadIdx.x] = 0.f;
  const int i4 = (blockIdx.x * 256 + threadIdx.x) << 2;
  const int c = i4 & 511;
  const bf16x4 rz = *(const bf16x4*)&resid16[i4];
  const float4 bi = *(const float4*)&bias[c];
  float o0 = (float)rz[0] + bi.x, o1 = (float)rz[1] + bi.y;
  float o2 = (float)rz[2] + bi.z, o3 = (float)rz[3] + bi.w;
#pragma unroll
  for (int s = 0; s < 8; s++) {
    const bf16x4 p = *(const bf16x4*)&parts[(size_t)s * BPSLICE + i4];
    o0 += (float)p[0];
    o1 += (float)p[1];
    o2 += (float)p[2];
    o3 += (float)p[3];
  }
  bf16x4 o16 = {(bf16)o0, (bf16)o1, (bf16)o2, (bf16)o3};
  *(bf16x4*)&xb16[i4] = o16;
}

// LN over 512 channels of (p0+p1 [+bias]); one wave/token, 4 tokens/block.
template <bool ENC>
__global__ __launch_bounds__(256) void ln_comb_k(
    const float* __restrict__ parts, const float* __restrict__ bias,
    const float* __restrict__ w, const float* __restrict__ b,
    const float* __restrict__ Wr, bf16* __restrict__ zraw16,
    bf16* __restrict__ out16, float* __restrict__ probs) {
  const int wv = threadIdx.x >> 6, lane = threadIdx.x & 63;
  const int n = (blockIdx.x << 2) + wv;
  float v[8];
  float s = 0.f, s2 = 0.f;
#pragma unroll
  for (int i = 0; i < 8; i++) {
    const int c = (i << 6) + lane;
    float x = parts[(size_t)n * 512 + c] + parts[PSLICE + (size_t)n * 512 + c];
    if constexpr (ENC) x += bias[c];
    v[i] = x;
    s += x;
    s2 += x * x;
  }
#pragma unroll
  for (int off = 32; off > 0; off >>= 1) {
    s += __shfl_down(s, off);
    s2 += __shfl_down(s2, off);
  }
  s = __shfl(s, 0);
  s2 = __shfl(s2, 0);
  const float m = s * (1.f / 512.f);
  const float var = s2 * (1.f / 512.f) - m * m;
  const float r = rsqrtf(var + 1e-5f);
  float a0 = 0.f, a1 = 0.f, a2 = 0.f, a3 = 0.f;
#pragma unroll
  for (int i = 0; i < 8; i++) {
    const int c = (i << 6) + lane;
    const float o = (v[i] - m) * r * w[c] + b[c];
    if constexpr (ENC) zraw16[(size_t)n * 512 + c] = (bf16)v[i];
    out16[(size_t)n * 512 + c] = (bf16)o;
    if constexpr (!ENC) {
      a0 += o * Wr[c * 4 + 0];
      a1 += o * Wr[c * 4 + 1];
      a2 += o * Wr[c * 4 + 2];
      a3 += o * Wr[c * 4 + 3];
    }
  }
  if constexpr (!ENC) {
#pragma unroll
    for (int off = 32; off > 0; off >>= 1) {
      a0 += __shfl_down(a0, off);
      a1 += __shfl_down(a1, off);
      a2 += __shfl_down(a2, off);
      a3 += __shfl_down(a3, off);
    }
    if (lane == 0) {
      const float mx = fmaxf(fmaxf(a0, a1), fmaxf(a2, a3));
      const float e0 = expf(a0 - mx), e1 = expf(a1 - mx), e2 = expf(a2 - mx),
                  e3 = expf(a3 - mx);
      const float inv = 1.f / (e0 + e1 + e2 + e3);
      probs[n * 4 + 0] = e0 * inv;
      probs[n * 4 + 1] = e1 * inv;
      probs[n * 4 + 2] = e2 * inv;
      probs[n * 4 + 3] = e3 * inv;
    }
  }
}

// final residual v = xb + xn + sum(8 bf16 MoE2 partials).
// DO_LN: raw -> zraw16 + LN(ln_sp next layer) -> out16.  else: out16 = bf16(v).
template <bool DO_LN>
__global__ __launch_bounds__(256) void addf2_k(
    const bf16* __restrict__ xb16, const bf16* __restrict__ xn16,
    const bf16* __restrict__ parts, const float* __restrict__ w,
    const float* __restrict__ b, bf16* __restrict__ zraw16,
    bf16* __restrict__ out16) {
  const int wv = threadIdx.x >> 6, lane = threadIdx.x & 63;
  const int n = (blockIdx.x << 2) + wv;
  float v[8];
  float s = 0.f, s2 = 0.f;
#pragma unroll
  for (int i = 0; i < 8; i++) {
    const size_t idx = (size_t)n * 512 + (i << 6) + lane;
    float x = (float)xb16[idx] + (float)xn16[idx];
#pragma unroll
    for (int sl = 0; sl < 8; sl++)
      x += (float)parts[(size_t)sl * BPSLICE + idx];
    v[i] = x;
    s += x;
    s2 += x * x;
  }
  if constexpr (!DO_LN) {
#pragma unroll
    for (int i = 0; i < 8; i++)
      out16[(size_t)n * 512 + (i << 6) + lane] = (bf16)v[i];
    return;
  }
#pragma unroll
  for (int off = 32; off > 0; off >>= 1) {
    s += __shfl_down(s, off);
    s2 += __shfl_down(s2, off);
  }
  s = __shfl(s, 0);
  s2 = __shfl(s2, 0);
  const float m = s * (1.f / 512.f);
  const float var = s2 * (1.f / 512.f) - m * m;
  const float r = rsqrtf(var + 1e-5f);
#pragma unroll
  for (int i = 0; i < 8; i++) {
    const int c = (i << 6) + lane;
    zraw16[(size_t)n * 512 + c] = (bf16)v[i];
    out16[(size_t)n * 512 + c] = (bf16)((v[i] - m) * r * w[c] + b[c]);
  }
}

// ---------- merged conversions: one launch, block-range decode ----------
__global__ __launch_bounds__(256) void cvt_all_k(
    const float* __restrict__ x, const float* __restrict__ Wenc,
    const float* __restrict__ Wdec, const float* __restrict__ W1,
    const float* __restrict__ W2, const float* __restrict__ E_re,
    const float* __restrict__ E_im, const float* __restrict__ Ed_re,
    const float* __restrict__ Ed_im, const float* __restrict__ conv_w,
    bf16* __restrict__ Ae, bf16* __restrict__ WencT, bf16* __restrict__ WdecT,
    bf16* __restrict__ W1T, bf16* __restrict__ W2Tc, bf16* __restrict__ MEt,
    bf16* __restrict__ convBt) {
  __shared__ float smem[4608];
  float(*tile)[33] = (float(*)[33])smem;
  const int tid = threadIdx.x;
  int b = blockIdx.x;
  const int tx = tid & 31, ty = tid >> 5;
  auto tpose = [&](const float* src, bf16* dst, int N, int dstride, int k0,
                   int n0) {
#pragma unroll
    for (int r = 0; r < 4; r++)
      tile[ty + 8 * r][tx] = src[(size_t)(k0 + ty + 8 * r) * N + n0 + tx];
    __syncthreads();
#pragma unroll
    for (int r = 0; r < 4; r++)
      dst[(size_t)(n0 + ty + 8 * r) * dstride + k0 + tx] =
          (bf16)tile[tx][ty + 8 * r];
  };
  if (b < 1024) {  // encoder patch gather + cast
    const int id = b * 256 + tid;
    const int n = id >> 7;
    const int kc = (id & 127) << 3;
    const int t = n >> 8, hp = (n >> 4) & 15, wp = n & 15;
    const int c = kc >> 8, ph = (kc >> 4) & 15, pw = kc & 15;
    const float* src =
        &x[(size_t)(((t * 4 + c) * 256 + hp * 16 + ph) << 8) + wp * 16 + pw];
    const float4 v0 = *(const float4*)src;
    const float4 v1 = *(const float4*)(src + 4);
    bf16* d = &Ae[(size_t)n * 1024 + kc];
    d[0] = (bf16)v0.x; d[1] = (bf16)v0.y; d[2] = (bf16)v0.z; d[3] = (bf16)v0.w;
    d[4] = (bf16)v1.x; d[5] = (bf16)v1.y; d[6] = (bf16)v1.z; d[7] = (bf16)v1.w;
    return;
  }
  b -= 1024;
  if (b < 512) {
    tpose(Wenc, WencT, 512, 1024, (b & 31) * 32, (b >> 5) * 32);
    return;
  }
  b -= 512;
  if (b < 512) {
    tpose(Wdec, WdecT, 1024, 512, (b & 15) * 32, (b >> 4) * 32);
    return;
  }
  b -= 512;
  if (b < 4096) {
    const int z = b >> 9, rem = b & 511;
    tpose(W1 + (size_t)z * 524288, W1T + (size_t)z * 524288, 1024, 512,
          (rem & 15) * 32, (rem >> 4) * 32);
    return;
  }
  b -= 4096;
  if (b < 4096) {
    const int z = b >> 9, rem = b & 511;
    const int l = z >> 2, e = z & 3;
    tpose(W2 + (size_t)z * 524288, W2Tc + (size_t)l * 2097152 + e * 1024, 512,
          4096, (rem & 31) * 32, (rem >> 5) * 32);
    return;
  }
  b -= 4096;
  if (b < 4096) {
    const int z = b >> 10;
    const int l = z >> 1, which = z & 1;
    const float* Er = (which ? Ed_re : E_re) + l * 65536;
    const float* Ei = (which ? Ed_im : E_im) + l * 65536;
    bf16* dst = MEt + (size_t)z * 262144;
    const int idx = (b & 1023) * 256 + tid;
    const int j = idx >> 9, k = idx & 511;
    const int kk = k & 255, jj = j & 255;
    const float er = Er[kk * 256 + jj], ei = Ei[kk * 256 + jj];
    const float v = (k < 256) ? ((j < 256) ? er : ei) : ((j < 256) ? -ei : er);
    dst[idx] = (bf16)v;
    return;
  }
  b -= 4096;
  {  // conv_w: one block per (l,co); coalesced read -> LDS -> coalesced write
    const int l = b >> 9, co = b & 511;
    const float* src = conv_w + (size_t)l * 2359296 + (size_t)co * 4608;
    bf16* d = convBt + (size_t)l * 2359296 + (size_t)co * 4608;
    for (int i = tid; i < 4608; i += 256) smem[i] = src[i];
    __syncthreads();
    for (int o = tid; o < 4608; o += 256) {
      const int s = o >> 9, ci = o & 511;
      d[o] = (bf16)smem[ci * 9 + s];
    }
  }
}

// Parallel src/gate from precomputed xmean sums. grid (8 t, 3 part) x 256.
__global__ __launch_bounds__(256) void srcgate_k(
    const float* __restrict__ xmean, const float* __restrict__ Wsr,
    const float* __restrict__ Wsi, const float* __restrict__ Wg,
    const float* __restrict__ bg, float* __restrict__ srcs,
    float* __restrict__ gts) {
  const int t = blockIdx.x, part = blockIdx.y, d = threadIdx.x;
  __shared__ float sxm[512];
  for (int c = d; c < 512; c += 256) sxm[c] = xmean[t * 512 + c] * (1.f / 256.f);
  __syncthreads();
  if (part == 0) {
    float s0 = 0.f, s1 = 0.f, s2 = 0.f, s3 = 0.f;
#pragma unroll 4
    for (int e = 0; e < 256; e += 4) {
      s0 += sxm[e + 0] * Wsr[(e + 0) * 256 + d] - sxm[256 + e + 0] * Wsi[(e + 0) * 256 + d];
      s1 += sxm[e + 1] * Wsr[(e + 1) * 256 + d] - sxm[256 + e + 1] * Wsi[(e + 1) * 256 + d];
      s2 += sxm[e + 2] * Wsr[(e + 2) * 256 + d] - sxm[256 + e + 2] * Wsi[(e + 2) * 256 + d];
      s3 += sxm[e + 3] * Wsr[(e + 3) * 256 + d] - sxm[256 + e + 3] * Wsi[(e + 3) * 256 + d];
    }
    srcs[t * 512 + d] = (s0 + s1) + (s2 + s3);
  } else if (part == 1) {
    float s0 = 0.f, s1 = 0.f, s2 = 0.f, s3 = 0.f;
#pragma unroll 4
    for (int e = 0; e < 256; e += 4) {
      s0 += sxm[e + 0] * Wsi[(e + 0) * 256 + d] + sxm[256 + e + 0] * Wsr[(e + 0) * 256 + d];
      s1 += sxm[e + 1] * Wsi[(e + 1) * 256 + d] + sxm[256 + e + 1] * Wsr[(e + 1) * 256 + d];
      s2 += sxm[e + 2] * Wsi[(e + 2) * 256 + d] + sxm[256 + e + 2] * Wsr[(e + 2) * 256 + d];
      s3 += sxm[e + 3] * Wsi[(e + 3) * 256 + d] + sxm[256 + e + 3] * Wsr[(e + 3) * 256 + d];
    }
    srcs[t * 512 + 256 + d] = (s0 + s1) + (s2 + s3);
  } else {
    float s0 = 0.f, s1 = 0.f, s2 = 0.f, s3 = 0.f;
#pragma unroll 4
    for (int c = 0; c < 512; c += 4) {
      s0 += sxm[c + 0] * Wg[(c + 0) * 256 + d];
      s1 += sxm[c + 1] * Wg[(c + 1) * 256 + d];
      s2 += sxm[c + 2] * Wg[(c + 2) * 256 + d];
      s3 += sxm[c + 3] * Wg[(c + 3) * 256 + d];
    }
    const float ga = (s0 + s1) + (s2 + s3) + bg[d];
    gts[t * 256 + d] = 1.f / (1.f + expf(-ga));
  }
}

// Per-(p,d) time scan over esq1 fp32 partials (2 slices); opd/opf inline.
template <bool FIRST>
__global__ __launch_bounds__(256) void time_scan_k(
    const float* __restrict__ parts, const float* __restrict__ gts,
    const float* __restrict__ srcs, const float* __restrict__ lamre,
    const float* __restrict__ lamim, const float* __restrict__ dt,
    bf16* __restrict__ hout16, float* __restrict__ hprev) {
  const int d = threadIdx.x;
  const int p = blockIdx.x;
  const float lr0 = lamre[d];
  const float sp = (lr0 > 20.f) ? lr0 : log1pf(expf(lr0));
  const float lre = -(sp + 0.01f);
  const float lim = lamim[d];
  const float den = lre * lre + lim * lim;
  float ar[8], ai[8], ofr[8], ofi[8];
#pragma unroll
  for (int t = 0; t < 8; t++) {
    const float dtv = dt[t];
    const float er = expf(lre * dtv);
    const float odr = er * cosf(lim * dtv);
    const float odi = er * sinf(lim * dtv);
    ar[t] = odr;
    ai[t] = odi;
    const float nr = odr - 1.f, ni = odi;
    ofr[t] = (nr * lre + ni * lim) / den;
    ofi[t] = (ni * lre - nr * lim) / den;
  }
  float hr = 0.f, hi = 0.f;
  float hpr = 0.f, hpi = 0.f;
  if constexpr (!FIRST) {
    hpr = hprev[p * 512 + d];
    hpi = hprev[p * 512 + 256 + d];
  }
  float o7r = 0.f, o7i = 0.f;
#pragma unroll
  for (int t = 0; t < 8; t++) {
    const size_t base = (size_t)((t << 8) + p) * 512;
    const float xr = parts[base + d] + parts[PSLICE + base + d];
    const float xi = parts[base + 256 + d] + parts[PSLICE + base + 256 + d];
    const float g = gts[t * 256 + d];
    const float sr = srcs[t * 512 + d], si = srcs[t * 512 + 256 + d];
    const float fr = xr * g + sr * (1.f - g);
    const float fi = xi * g + si * (1.f - g);
    const float ur = fr * ofr[t] - fi * ofi[t];
    const float ui = fr * ofi[t] + fi * ofr[t];
    const float nhr = ur + ar[t] * hr - ai[t] * hi;
    const float nhi = ui + ar[t] * hi + ai[t] * hr;
    hr = nhr;
    hi = nhi;
    const float outr = hr + ar[t] * hpr - ai[t] * hpi;
    const float outi = hi + ar[t] * hpi + ai[t] * hpr;
    hout16[base + d] = (bf16)outr;
    hout16[base + 256 + d] = (bf16)outi;
    if (t == 7) {
      o7r = outr;
      o7i = outi;
    }
  }
  hprev[p * 512 + d] = o7r;
  hprev[p * 512 + 256 + d] = o7i;
}

extern "C" void kernel_launch(void* const* d_in, const int* in_sizes, int n_in,
                              void* d_out, int out_size, void* d_ws,
                              size_t ws_size, hipStream_t stream) {
  const float* x_in = (const float*)d_in[0];
  const float* dt = (const float*)d_in[1];
  const float* Wenc = (const float*)d_in[2];
  const float* benc = (const float*)d_in[3];
  const float* Wdec = (const float*)d_in[4];
  const float* bdec = (const float*)d_in[5];
  const float* ln_sp_w = (const float*)d_in[6];
  const float* ln_sp_b = (const float*)d_in[7];
  const float* conv_w = (const float*)d_in[8];
  const float* conv_b = (const float*)d_in[9];
  const float* E_re = (const float*)d_in[10];
  const float* E_im = (const float*)d_in[11];
  const float* Ed_re = (const float*)d_in[12];
  const float* Ed_im = (const float*)d_in[13];
  const float* Ws_re = (const float*)d_in[14];
  const float* Ws_im = (const float*)d_in[15];
  const float* Wg = (const float*)d_in[16];
  const float* bg = (const float*)d_in[17];
  const float* lam_re = (const float*)d_in[18];
  const float* lam_im = (const float*)d_in[19];
  const float* ln_t_w = (const float*)d_in[20];
  const float* ln_t_b = (const float*)d_in[21];
  const float* Wr = (const float*)d_in[22];
  const float* W1 = (const float*)d_in[23];
  const float* W2 = (const float*)d_in[24];
  float* out = (float*)d_out;

  float* ws = (float*)d_ws;
  size_t off = 0;
  auto allocf = [&](size_t n) {
    float* p = ws + off;
    off += n;
    return p;
  };
  auto allocb = [&](size_t n) {
    bf16* p = (bf16*)(ws + off);
    off += n / 2;
    return p;
  };
  float* parts = allocf((size_t)2 * PSLICE);     // fp32 partials (enc/esq)
  bf16* bparts = allocb((size_t)8 * BPSLICE);    // bf16 partials (conv/moe2)
  float* hprev = allocf(256 * 512);
  float* xm = allocf(8 * 512);
  float* srcs = allocf(8 * 512);
  float* gts = allocf(8 * 256);
  float* probs = allocf((size_t)TOKS * 4);
  bf16* zraw16 = allocb((size_t)TOKS * 512);
  bf16* znsp16 = allocb((size_t)TOKS * 512);
  bf16* xn16 = allocb((size_t)TOKS * 512);
  bf16* xb16 = allocb((size_t)TOKS * 512);
  bf16* z16 = allocb((size_t)TOKS * 512);
  bf16* hb16 = allocb((size_t)TOKS * 512);
  bf16* hid16 = allocb((size_t)TOKS * 4096);
  bf16* Aenc16 = allocb((size_t)TOKS * 1024);
  bf16* WencT = allocb((size_t)512 * 1024);
  bf16* WdecT = allocb((size_t)1024 * 512);
  bf16* MEt = allocb((size_t)4 * 512 * 512);
  bf16* convBt = allocb((size_t)2 * 512 * 4608);
  bf16* W1T = allocb((size_t)8 * 1024 * 512);
  bf16* W2Tc = allocb((size_t)2 * 512 * 4096);

  // ---- all conversions in one launch ----
  cvt_all_k<<<15360, 256, 0, stream>>>(x_in, Wenc, Wdec, W1, W2, E_re, E_im,
                                       Ed_re, Ed_im, conv_w, Aenc16, WencT,
                                       WdecT, W1T, W2Tc, MEt, convBt);

  // ---- encoder: split-K=2, combine folded into LN ----
  mgemm_k<EENC, 2, false><<<dim3(32, 8, 2), 256, 0, stream>>>(
      Aenc16, WencT, nullptr, nullptr, nullptr, nullptr, parts, nullptr,
      nullptr, 1024, 512);
  ln_comb_k<true><<<512, 256, 0, stream>>>(parts, benc, ln_sp_w, ln_sp_b,
                                           nullptr, zraw16, znsp16, nullptr);

  for (int l = 0; l < 2; l++) {
    mgemm_k<ECONV, 8, true><<<dim3(32, 8, 8), 256, 0, stream>>>(
        znsp16, convBt + (size_t)l * 2359296, nullptr, nullptr, nullptr,
        nullptr, nullptr, bparts, nullptr, 4608, 512);
    conv_ep_k<<<1024, 256, 0, stream>>>(bparts, conv_b + l * 512, zraw16, xb16,
                                        xm);
    mgemm_k<ESQM, 2, false><<<dim3(32, 8, 2), 256, 0, stream>>>(
        xb16, MEt + (size_t)(l * 2) * 262144, nullptr, nullptr, nullptr,
        nullptr, parts, nullptr, xm, 512, 512);
    srcgate_k<<<dim3(8, 3), 256, 0, stream>>>(xm, Ws_re + l * 65536,
                                              Ws_im + l * 65536,
                                              Wg + l * 131072, bg + l * 256,
                                              srcs, gts);
    if (l == 0)
      time_scan_k<true><<<256, 256, 0, stream>>>(parts, gts, srcs, lam_re,
                                                 lam_im, dt, hb16, hprev);
    else
      time_scan_k<false><<<256, 256, 0, stream>>>(parts, gts, srcs,
                                                  lam_re + 256, lam_im + 256,
                                                  dt, hb16, hprev);
    mgemm_k<ESQ, 2, false><<<dim3(32, 8, 2), 256, 0, stream>>>(
        hb16, MEt + (size_t)(l * 2 + 1) * 262144, nullptr, nullptr, nullptr,
        nullptr, parts, nullptr, nullptr, 512, 512);
    ln_comb_k<false><<<512, 256, 0, stream>>>(parts, nullptr, ln_t_w + l * 512,
                                              ln_t_b + l * 512, Wr + l * 2048,
                                              nullptr, xn16, probs);
    mgemm_k<EMOE1, 1, false><<<dim3(32, 16, 4), 256, 0, stream>>>(
        xn16, W1T + (size_t)l * 2097152, nullptr, probs, nullptr, hid16,
        nullptr, nullptr, nullptr, 512, 1024);
    mgemm_k<EMOE2, 8, true><<<dim3(32, 8, 8), 256, 0, stream>>>(
        hid16, W2Tc + (size_t)l * 2097152, nullptr, nullptr, nullptr, nullptr,
        nullptr, bparts, nullptr, 4096, 512);
    if (l == 0)
      addf2_k<true><<<512, 256, 0, stream>>>(xb16, xn16, bparts, ln_sp_w + 512,
                                             ln_sp_b + 512, zraw16, znsp16);
    else
      addf2_k<false><<<512, 256, 0, stream>>>(xb16, xn16, bparts, nullptr,
                                              nullptr, nullptr, z16);
  }

  // ---- decoder ----
  mgemm_k<EDEC, 1, false><<<dim3(32, 16), 256, 0, stream>>>(
      z16, WdecT, bdec, nullptr, out, nullptr, nullptr, nullptr, nullptr, 512,
      1024);
}